// Round 5
// baseline (228.184 us; speedup 1.0000x reference)
//
#include <hip/hip_runtime.h>

#define NUM_GRAPHS 64
#define CHUNK_NODES 10112
#define CHUNK_FLOATS (CHUNK_NODES * 3)   // 30336 floats = 121,344 B
#define BLOCK 1024
#define WAVES (BLOCK / 64)               // 16
#define QCAP 320                         // peak fill = 255 + 64 (check per step) = 319
#define DRAIN_K 256
#define SLICES 24                        // grid = 240 <= 256 CUs, %8==0 for XCD swizzle

// LDS: facc 121,344 + queues 16*320*8 = 40,960 + ebins 256 = 162,560 B -> 1 block/CU,
// 16 waves/CU (4/SIMD). Queue entries are fat (iv|jv|flags in 64b) so the drain
// never touches edge_index; drain processes 256 entries with 4-way ILP per lane.
__global__ __launch_bounds__(BLOCK, 4) void edge_scan_kernel(
    const float* __restrict__ pos,      // [N,3]
    const int*   __restrict__ ei,       // [2,E]
    const int*   __restrict__ batch,    // [N]
    float*       __restrict__ energy,   // d_out[0..63], pre-zeroed
    float*       __restrict__ partials, // ws: [slices*chunks][CHUNK_FLOATS]
    int E, int chunks, int slices, int per_slice, int swizzle)
{
    __shared__ float facc[CHUNK_FLOATS];
    __shared__ float ebins[NUM_GRAPHS];
    __shared__ unsigned long long q[WAVES][QCAP];

    const int t    = threadIdx.x;
    const int lane = t & 63;
    const int w    = t >> 6;

    for (int idx = 4 * t; idx < CHUNK_FLOATS; idx += 4 * BLOCK) {
        float4 z = {0.f, 0.f, 0.f, 0.f};
        *(float4*)&facc[idx] = z;
    }
    if (t < NUM_GRAPHS) ebins[t] = 0.f;
    __syncthreads();

    // XCD swizzle: same-slice blocks cluster on one XCD so the slice's edge
    // rows stay L2-resident across the `chunks` re-reads.
    int chunk, slice;
    const int b = blockIdx.x;
    if (swizzle) {
        const int g = b & 7;
        const int k = b >> 3;
        slice = g + 8 * (k / chunks);
        chunk = k % chunks;
    } else {
        chunk = b % chunks;
        slice = b / chunks;
    }

    const int lo      = chunk * CHUNK_NODES;
    const int e_begin = slice * per_slice;
    const int e_end   = min(E, e_begin + per_slice);

    unsigned int head = 0, tail = 0, cnt = 0;   // wave-uniform

    // Drain up to 256 entries; lane handles entries head+lane+64u, u=0..3.
    // Phase 1 issues all LDS reads + pos gathers (high MLP); phase 2 computes.
    auto drain = [&](unsigned int k) {
        __builtin_amdgcn_wave_barrier();        // order queue writes vs reads
        int   iv[4], jv[4], fi[4], fj[4], bt[4];
        float xi[4], yi[4], zi[4], xj[4], yj[4], zj[4];
        #pragma unroll
        for (int u = 0; u < 4; ++u) {
            const unsigned int idx = (unsigned int)(lane + (u << 6));
            fi[u] = 0; fj[u] = 0;
            if (idx < k) {
                unsigned int qp = head + idx; if (qp >= QCAP) qp -= QCAP;
                const unsigned long long e = q[w][qp];
                iv[u] = (int)(e & 0x1FFFF);
                jv[u] = (int)((e >> 17) & 0x1FFFF);
                fi[u] = (int)((e >> 34) & 1);
                fj[u] = (int)((e >> 35) & 1);
                xi[u] = pos[3*iv[u]+0]; yi[u] = pos[3*iv[u]+1]; zi[u] = pos[3*iv[u]+2];
                xj[u] = pos[3*jv[u]+0]; yj[u] = pos[3*jv[u]+1]; zj[u] = pos[3*jv[u]+2];
                bt[u] = batch[iv[u]];
            }
        }
        #pragma unroll
        for (int u = 0; u < 4; ++u) {
            const unsigned int idx = (unsigned int)(lane + (u << 6));
            if (idx < k) {
                const float dx = xi[u] - xj[u];
                const float dy = yi[u] - yj[u];
                const float dz = zi[u] - zj[u];
                const float d     = sqrtf(dx*dx + dy*dy + dz*dz);
                const float delta = d - 1.0f;                 // R0 = 1
                const float s     = delta / (d + 1e-20f);     // K = 1
                const float fx = s*dx, fy = s*dy, fz = s*dz;
                if (fi[u]) {
                    atomicAdd(&ebins[bt[u]], 0.5f * delta * delta);
                    const int l = (iv[u] - lo) * 3;
                    atomicAdd(&facc[l+0], -fx);
                    atomicAdd(&facc[l+1], -fy);
                    atomicAdd(&facc[l+2], -fz);
                }
                if (fj[u]) {
                    const int l = (jv[u] - lo) * 3;
                    atomicAdd(&facc[l+0], fx);
                    atomicAdd(&facc[l+1], fy);
                    atomicAdd(&facc[l+2], fz);
                }
            }
        }
        head += k; if (head >= QCAP) head -= QCAP;
        cnt  -= k;
    };

    auto load4 = [&](int e0, int4& a, int4& c) {
        if (e0 + 3 < e_end) {
            a = *(const int4*)(ei + e0);
            c = *(const int4*)(ei + E + e0);
        } else {
            const int sent = 0x7fffffff;   // fails the in-chunk test
            a.x = (e0     < e_end) ? ei[e0]       : sent;
            a.y = (e0 + 1 < e_end) ? ei[e0 + 1]   : sent;
            a.z = (e0 + 2 < e_end) ? ei[e0 + 2]   : sent;
            a.w = (e0 + 3 < e_end) ? ei[e0 + 3]   : sent;
            c.x = (e0     < e_end) ? ei[E+e0]     : sent;
            c.y = (e0 + 1 < e_end) ? ei[E+e0 + 1] : sent;
            c.z = (e0 + 2 < e_end) ? ei[E+e0 + 2] : sent;
            c.w = (e0 + 3 < e_end) ? ei[E+e0 + 3] : sent;
        }
    };

    int base = e_begin + 256 * w;
    int4 ii, jj;
    if (base < e_end) load4(base + 4 * lane, ii, jj);

    for (; base < e_end; ) {
        const int nbase = base + 4 * BLOCK;
        int4 iin, jjn;
        if (nbase < e_end) load4(nbase + 4 * lane, iin, jjn);   // prefetch

        #pragma unroll
        for (int s = 0; s < 4; ++s) {
            const int av = (s == 0) ? ii.x : (s == 1) ? ii.y : (s == 2) ? ii.z : ii.w;
            const int bv = (s == 0) ? jj.x : (s == 1) ? jj.y : (s == 2) ? jj.z : jj.w;
            const unsigned int ini = (unsigned int)(av - lo) < CHUNK_NODES;
            const unsigned int inj = (unsigned int)(bv - lo) < CHUNK_NODES;
            const bool p = (ini | inj) != 0;
            const unsigned long long m = __ballot(p);
            if (p) {
                const unsigned int off = __popcll(m & ((1ull << lane) - 1ull));
                unsigned int qp = tail + off; if (qp >= QCAP) qp -= QCAP;
                q[w][qp] = (unsigned long long)(unsigned int)av
                         | ((unsigned long long)(unsigned int)bv << 17)
                         | ((unsigned long long)ini << 34)
                         | ((unsigned long long)inj << 35);
            }
            const unsigned int c = (unsigned int)__popcll(m);
            tail += c; if (tail >= QCAP) tail -= QCAP;
            cnt  += c;
            if (cnt >= DRAIN_K) drain(DRAIN_K);
        }
        base = nbase; ii = iin; jj = jjn;
    }
    while (cnt > 0) drain(cnt < DRAIN_K ? cnt : DRAIN_K);

    __syncthreads();
    float* dst = partials + (size_t)(slice * chunks + chunk) * CHUNK_FLOATS;
    for (int idx = 4 * t; idx < CHUNK_FLOATS; idx += 4 * BLOCK)
        *(float4*)(dst + idx) = *(const float4*)&facc[idx];
    if (t < NUM_GRAPHS) atomicAdd(&energy[t], ebins[t]);
}

// Pass B: forces[f] = sum over slices of the chunk-partial holding f. float4.
__global__ __launch_bounds__(256) void reduce_kernel(
    const float* __restrict__ partials,
    float*       __restrict__ forces,
    int total_floats, int chunks, int slices)
{
    const int f4 = (blockIdx.x * 256 + threadIdx.x) * 4;
    if (f4 >= total_floats) return;
    const int chunk = f4 / CHUNK_FLOATS;   // CHUNK_FLOATS % 4 == 0
    const int rem   = f4 - chunk * CHUNK_FLOATS;
    float4 sum = {0.f, 0.f, 0.f, 0.f};
    for (int s = 0; s < slices; ++s) {
        const float4 v = *(const float4*)&partials[(size_t)(s * chunks + chunk) * CHUNK_FLOATS + rem];
        sum.x += v.x; sum.y += v.y; sum.z += v.z; sum.w += v.w;
    }
    *(float4*)&forces[f4] = sum;
}

extern "C" void kernel_launch(void* const* d_in, const int* in_sizes, int n_in,
                              void* d_out, int out_size, void* d_ws, size_t ws_size,
                              hipStream_t stream) {
    const float* pos   = (const float*)d_in[0];
    const int*   ei    = (const int*)d_in[1];
    const int*   batch = (const int*)d_in[2];

    const int E = in_sizes[1] / 2;     // edge_index is [2, E]
    const int N = in_sizes[0] / 3;     // pos is [N, 3]

    float* energy = (float*)d_out;            // first 64 floats
    float* forces = (float*)d_out + NUM_GRAPHS;

    const int chunks = (N + CHUNK_NODES - 1) / CHUNK_NODES;   // 10 for N=100000

    const size_t slice_bytes = (size_t)chunks * CHUNK_FLOATS * sizeof(float);
    int slices = SLICES;
    int swizzle = 1;
    if ((size_t)slices * slice_bytes > ws_size) {
        slices = (int)(ws_size / slice_bytes);
        if (slices < 1) slices = 1;
        swizzle = 0;
    }
    // per_slice multiple of 4096 keeps scan int4 loads aligned & in-slice
    int per_slice = (E + slices - 1) / slices;
    per_slice = (per_slice + 4095) & ~4095;

    // Only energy accumulates via atomics into d_out; forces fully overwritten.
    hipMemsetAsync(d_out, 0, NUM_GRAPHS * sizeof(float), stream);

    edge_scan_kernel<<<chunks * slices, BLOCK, 0, stream>>>(
        pos, ei, batch, energy, (float*)d_ws, E, chunks, slices, per_slice, swizzle);

    const int total_floats = 3 * N;   // 300000, divisible by 4
    reduce_kernel<<<(total_floats / 4 + 255) / 256, 256, 0, stream>>>(
        (const float*)d_ws, forces, total_floats, chunks, slices);
}

// Round 6
// 224.675 us; speedup vs baseline: 1.0156x; 1.0156x over previous
//
#include <hip/hip_runtime.h>

#define NUM_GRAPHS 64
#define CHUNKS 16
#define CHUNK_NODES 6400
#define CHUNK_FLOATS (CHUNK_NODES * 3)    // 19200 floats = 76.8 KB LDS
#define SCAN_BLOCKS 512
#define SCAN_THREADS 1024
#define GROUPS 16
#define RPG (SCAN_BLOCKS / GROUPS)        // 32 regions per accumulate block

// ---------------------------------------------------------------------------
// P0: pack pos[N,3] + batch[N] -> pos4[N] = {x,y,z, bits(batch)}.
// Every later endpoint gather becomes a single dwordx4 (one cache line).
__global__ __launch_bounds__(256) void pack_kernel(
    const float* __restrict__ pos, const int* __restrict__ batch,
    float4* __restrict__ pos4, int N)
{
    const int n = blockIdx.x * 256 + threadIdx.x;
    if (n < N) {
        float4 v;
        v.x = pos[3 * n + 0];
        v.y = pos[3 * n + 1];
        v.z = pos[3 * n + 2];
        v.w = __int_as_float(batch[n]);
        pos4[n] = v;
    }
}

// ---------------------------------------------------------------------------
// P1: single pass over edges. Each edge emits one u64 record per touched
// chunk (1 if both endpoints share a chunk, else 2). Slot reservation via
// per-block LDS cursors; records land in per-(block,chunk) regions of ws.
// Record: iv | jv<<17 | fi<<34 | fj<<35  (fi set on the chunk(i) record ->
// energy counted exactly once per edge).
__global__ __launch_bounds__(SCAN_THREADS) void scan_scatter_kernel(
    const int* __restrict__ ei,            // [2,E]
    unsigned long long* __restrict__ recs, // [SCAN_BLOCKS*CHUNKS*cap]
    int* __restrict__ counts,              // [SCAN_BLOCKS*CHUNKS]
    int E, int cap, int per_block_groups)
{
    __shared__ int cur[CHUNKS];
    const int t = threadIdx.x;
    if (t < CHUNKS) cur[t] = 0;
    __syncthreads();

    const int b = blockIdx.x;
    const int ngroups = E >> 2;
    const int g_begin = b * per_block_groups;
    const int g_end   = min(ngroups, g_begin + per_block_groups);

    for (int g = g_begin + t; g < g_end; g += SCAN_THREADS) {
        const int4 iv4 = ((const int4*)ei)[g];
        const int4 jv4 = ((const int4*)(ei + E))[g];
        #pragma unroll
        for (int s = 0; s < 4; ++s) {
            const int iv = (s == 0) ? iv4.x : (s == 1) ? iv4.y : (s == 2) ? iv4.z : iv4.w;
            const int jv = (s == 0) ? jv4.x : (s == 1) ? jv4.y : (s == 2) ? jv4.z : jv4.w;
            const int ci = iv / CHUNK_NODES;   // compiler magic-mul
            const int cj = jv / CHUNK_NODES;
            const unsigned long long base =
                (unsigned long long)(unsigned int)iv |
                ((unsigned long long)(unsigned int)jv << 17);
            if (ci == cj) {
                const int off = atomicAdd(&cur[ci], 1);
                if (off < cap)
                    recs[(size_t)(b * CHUNKS + ci) * cap + off] =
                        base | (1ull << 34) | (1ull << 35);
            } else {
                const int o1 = atomicAdd(&cur[ci], 1);
                if (o1 < cap)
                    recs[(size_t)(b * CHUNKS + ci) * cap + o1] = base | (1ull << 34);
                const int o2 = atomicAdd(&cur[cj], 1);
                if (o2 < cap)
                    recs[(size_t)(b * CHUNKS + cj) * cap + o2] = base | (1ull << 35);
            }
        }
    }

    // tail edges (E % 4) — handled serially by last block (0 for E=3.2M)
    if (b == SCAN_BLOCKS - 1 && t == 0) {
        for (int e = ngroups << 2; e < E; ++e) {
            const int iv = ei[e], jv = ei[E + e];
            const int ci = iv / CHUNK_NODES, cj = jv / CHUNK_NODES;
            const unsigned long long base =
                (unsigned long long)(unsigned int)iv |
                ((unsigned long long)(unsigned int)jv << 17);
            if (ci == cj) {
                const int off = atomicAdd(&cur[ci], 1);
                if (off < cap)
                    recs[(size_t)(b * CHUNKS + ci) * cap + off] =
                        base | (1ull << 34) | (1ull << 35);
            } else {
                const int o1 = atomicAdd(&cur[ci], 1);
                if (o1 < cap)
                    recs[(size_t)(b * CHUNKS + ci) * cap + o1] = base | (1ull << 34);
                const int o2 = atomicAdd(&cur[cj], 1);
                if (o2 < cap)
                    recs[(size_t)(b * CHUNKS + cj) * cap + o2] = base | (1ull << 35);
            }
        }
    }

    __syncthreads();
    if (t < CHUNKS) counts[b * CHUNKS + t] = min(cur[t], cap);
}

// ---------------------------------------------------------------------------
// P2: dense accumulate. Block = (chunk c, group g); drains RPG regions of
// coalesced records, 2 records/lane ILP; forces into 76.8 KB LDS facc
// (2 blocks/CU -> 32 waves/CU); energy into LDS bins via pos4.w batch id.
__global__ __launch_bounds__(1024, 8) void accumulate_kernel(
    const float4* __restrict__ pos4,
    const unsigned long long* __restrict__ recs,
    const int* __restrict__ counts,
    float* __restrict__ energy,     // d_out[0..63], pre-zeroed
    float* __restrict__ partials,   // [CHUNKS*GROUPS][CHUNK_FLOATS]
    int cap)
{
    __shared__ float facc[CHUNK_FLOATS];
    __shared__ float ebins[NUM_GRAPHS];

    const int t = threadIdx.x;
    for (int idx = 4 * t; idx < CHUNK_FLOATS; idx += 4 * 1024) {
        float4 z = {0.f, 0.f, 0.f, 0.f};
        *(float4*)&facc[idx] = z;
    }
    if (t < NUM_GRAPHS) ebins[t] = 0.f;
    __syncthreads();

    const int c   = blockIdx.x % CHUNKS;
    const int grp = blockIdx.x / CHUNKS;
    const int lo  = c * CHUNK_NODES;

    for (int r = 0; r < RPG; ++r) {
        const int b   = grp * RPG + r;
        const int cnt = counts[b * CHUNKS + c];
        const unsigned long long* reg = recs + (size_t)(b * CHUNKS + c) * cap;

        for (int base = 0; base < cnt; base += 2048) {
            const int i0 = base + 2 * t;
            const bool v0 = i0 < cnt;
            const bool v1 = i0 + 1 < cnt;

            unsigned long long e0 = 0, e1 = 0;
            if (v1) {
                // 16B coalesced record load (region base 16-aligned, cap even)
                const ulonglong2 rr = *(const ulonglong2*)(reg + i0);
                e0 = rr.x; e1 = rr.y;
            } else if (v0) {
                e0 = reg[i0];
            }

            // phase 1: decode + gather (2-way ILP)
            int iv0 = 0, jv0 = 0, iv1 = 0, jv1 = 0;
            float4 pa0, pb0, pa1, pb1;
            if (v0) {
                iv0 = (int)(e0 & 0x1FFFF);
                jv0 = (int)((e0 >> 17) & 0x1FFFF);
                pa0 = pos4[iv0];
                pb0 = pos4[jv0];
            }
            if (v1) {
                iv1 = (int)(e1 & 0x1FFFF);
                jv1 = (int)((e1 >> 17) & 0x1FFFF);
                pa1 = pos4[iv1];
                pb1 = pos4[jv1];
            }

            // phase 2: compute + LDS atomics
            if (v0) {
                const float dx = pa0.x - pb0.x, dy = pa0.y - pb0.y, dz = pa0.z - pb0.z;
                const float d     = sqrtf(dx*dx + dy*dy + dz*dz);
                const float delta = d - 1.0f;                 // R0 = 1
                const float sc    = delta / (d + 1e-20f);     // K = 1
                const float fx = sc*dx, fy = sc*dy, fz = sc*dz;
                if (e0 & (1ull << 34)) {
                    atomicAdd(&ebins[__float_as_int(pa0.w)], 0.5f * delta * delta);
                    const int l = (iv0 - lo) * 3;
                    atomicAdd(&facc[l+0], -fx);
                    atomicAdd(&facc[l+1], -fy);
                    atomicAdd(&facc[l+2], -fz);
                }
                if (e0 & (1ull << 35)) {
                    const int l = (jv0 - lo) * 3;
                    atomicAdd(&facc[l+0], fx);
                    atomicAdd(&facc[l+1], fy);
                    atomicAdd(&facc[l+2], fz);
                }
            }
            if (v1) {
                const float dx = pa1.x - pb1.x, dy = pa1.y - pb1.y, dz = pa1.z - pb1.z;
                const float d     = sqrtf(dx*dx + dy*dy + dz*dz);
                const float delta = d - 1.0f;
                const float sc    = delta / (d + 1e-20f);
                const float fx = sc*dx, fy = sc*dy, fz = sc*dz;
                if (e1 & (1ull << 34)) {
                    atomicAdd(&ebins[__float_as_int(pa1.w)], 0.5f * delta * delta);
                    const int l = (iv1 - lo) * 3;
                    atomicAdd(&facc[l+0], -fx);
                    atomicAdd(&facc[l+1], -fy);
                    atomicAdd(&facc[l+2], -fz);
                }
                if (e1 & (1ull << 35)) {
                    const int l = (jv1 - lo) * 3;
                    atomicAdd(&facc[l+0], fx);
                    atomicAdd(&facc[l+1], fy);
                    atomicAdd(&facc[l+2], fz);
                }
            }
        }
    }

    __syncthreads();
    float* dst = partials + (size_t)(c * GROUPS + grp) * CHUNK_FLOATS;
    for (int idx = 4 * t; idx < CHUNK_FLOATS; idx += 4 * 1024)
        *(float4*)(dst + idx) = *(const float4*)&facc[idx];
    if (t < NUM_GRAPHS) atomicAdd(&energy[t], ebins[t]);
}

// ---------------------------------------------------------------------------
// P3: forces[f] = sum over groups of the chunk-partial holding f. float4.
__global__ __launch_bounds__(256) void reduce_kernel(
    const float* __restrict__ partials,
    float*       __restrict__ forces,
    int total_floats)
{
    const int f4 = (blockIdx.x * 256 + threadIdx.x) * 4;
    if (f4 >= total_floats) return;
    const int c   = f4 / CHUNK_FLOATS;
    const int rem = f4 - c * CHUNK_FLOATS;
    float4 sum = {0.f, 0.f, 0.f, 0.f};
    for (int g = 0; g < GROUPS; ++g) {
        const float4 v = *(const float4*)&partials[(size_t)(c * GROUPS + g) * CHUNK_FLOATS + rem];
        sum.x += v.x; sum.y += v.y; sum.z += v.z; sum.w += v.w;
    }
    *(float4*)&forces[f4] = sum;
}

// ---------------------------------------------------------------------------
extern "C" void kernel_launch(void* const* d_in, const int* in_sizes, int n_in,
                              void* d_out, int out_size, void* d_ws, size_t ws_size,
                              hipStream_t stream) {
    const float* pos   = (const float*)d_in[0];
    const int*   ei    = (const int*)d_in[1];
    const int*   batch = (const int*)d_in[2];

    const int E = in_sizes[1] / 2;     // edge_index is [2, E]
    const int N = in_sizes[0] / 3;     // pos is [N, 3]

    float* energy = (float*)d_out;            // first 64 floats
    float* forces = (float*)d_out + NUM_GRAPHS;

    // Region capacity: per-block edges EB -> mean records/region = EB*1.94/16;
    // use EB*2/16 * 1.5 (~ mean + 16 sigma) rounded up to even.
    const int ngroups   = E >> 2;
    const int per_block = (ngroups + SCAN_BLOCKS - 1) / SCAN_BLOCKS;   // int4 groups
    const int EB        = per_block * 4;
    int cap = (EB * 2 / CHUNKS) * 3 / 2;
    cap = (cap + 1) & ~1;                                              // even (16B region align)

    // ws layout: pos4 | recs | counts | partials
    char* w = (char*)d_ws;
    float4* pos4 = (float4*)w;
    size_t off = (size_t)N * 16;
    unsigned long long* recs = (unsigned long long*)(w + off);
    off += (size_t)SCAN_BLOCKS * CHUNKS * cap * 8;
    int* counts = (int*)(w + off);
    off += (size_t)SCAN_BLOCKS * CHUNKS * 4;    // 32 KB, keeps 16-alignment
    float* partials = (float*)(w + off);
    off += (size_t)CHUNKS * GROUPS * CHUNK_FLOATS * 4;
    // total ~98 MB; ws_size evidenced >= 150 MB in earlier rounds.

    // energy accumulates via atomics -> zero it; forces fully overwritten.
    hipMemsetAsync(d_out, 0, NUM_GRAPHS * sizeof(float), stream);

    pack_kernel<<<(N + 255) / 256, 256, 0, stream>>>(pos, batch, pos4, N);

    scan_scatter_kernel<<<SCAN_BLOCKS, SCAN_THREADS, 0, stream>>>(
        ei, recs, counts, E, cap, per_block);

    accumulate_kernel<<<CHUNKS * GROUPS, 1024, 0, stream>>>(
        pos4, recs, counts, energy, partials, cap);

    const int total_floats = 3 * N;   // 300000, divisible by 4
    reduce_kernel<<<(total_floats / 4 + 255) / 256, 256, 0, stream>>>(
        partials, forces, total_floats);
}